// Round 11
// baseline (569.713 us; speedup 1.0000x reference)
//
#include <hip/hip_runtime.h>
#include <hip/hip_bf16.h>

#define EPSV 1e-5f
#define BSH 4     // bucket = dst >> BSH (16 nodes/bucket)
#define SCAP 512  // slots per bucket (mean 256, +16 sigma)

typedef __attribute__((ext_vector_type(8))) short s16x8;
typedef __attribute__((ext_vector_type(4))) float f32x4;

static __device__ __forceinline__ unsigned short f2b(float f) {
    __hip_bfloat16 h = __float2bfloat16(f);
    return *reinterpret_cast<unsigned short*>(&h);
}

// ---------------- bucket-clustered linked-list graph build ----------------
// slot = bucket*SCAP + pos (bucket = dst>>4). A node's chain stays inside its
// bucket's 4KB region -> L2-resident during the aggregation walk.
// head[node] -> most recent slot; pk[slot] = {next_slot, src_node}

__global__ void k_link2(const int* __restrict__ src, const int* __restrict__ dst,
                        int* __restrict__ head, int* __restrict__ bcur,
                        int2* __restrict__ pk, int E) {
    int e = blockIdx.x * blockDim.x + threadIdx.x;
    if (e < E) {
        int d = dst[e];
        int b = d >> BSH;
        int pos = atomicAdd(&bcur[b], 1);
        int slot = (b << 9) + pos;  // SCAP=512
        int h = atomicExch(&head[d], slot);
        pk[slot] = make_int2(h, src[e]);
    }
}

__global__ void k_mark(const int* __restrict__ nidx, int* __restrict__ mark,
                       int* __restrict__ list, int* __restrict__ nmarked, int M) {
    int m = blockIdx.x * blockDim.x + threadIdx.x;
    if (m < M) {
        int n = nidx[m];
        if (atomicExch(&mark[n], 1) == 0) list[atomicAdd(nmarked, 1)] = n;
    }
}

// ---------------- conversions ----------------

__global__ void k_tobf16(const float* __restrict__ in, unsigned short* __restrict__ out, int n4) {
    int i = blockIdx.x * blockDim.x + threadIdx.x;
    int stride = gridDim.x * blockDim.x;
    for (; i < n4; i += stride) {
        float4 v = ((const float4*)in)[i];
        ushort4 u;
        u.x = f2b(v.x); u.y = f2b(v.y); u.z = f2b(v.z); u.w = f2b(v.w);
        ((ushort4*)out)[i] = u;
    }
}

// offsets: W1l 0, W1r 16384, W2l 32768, W2r 49152, fcW1 65536, fcW2 81920 (total 90112)
__global__ void k_wconv(const float* __restrict__ W1l, const float* __restrict__ W1r,
                        const float* __restrict__ W2l, const float* __restrict__ W2r,
                        const float* __restrict__ fcW1, const float* __restrict__ fcW2,
                        unsigned short* __restrict__ Wb) {
    int i = blockIdx.x * blockDim.x + threadIdx.x;
    if (i >= 90112) return;
    float v;
    if (i < 16384) v = W1l[i];
    else if (i < 32768) v = W1r[i - 16384];
    else if (i < 49152) v = W2l[i - 32768];
    else if (i < 65536) v = W2r[i - 49152];
    else if (i < 81920) v = fcW1[i - 65536];
    else v = fcW2[i - 81920];
    Wb[i] = f2b(v);
}

// ---------------- aggregation: 16-lane-group dwordx4 chain walk ----------------
__global__ void k_aggr_g(const int* __restrict__ head, const int2* __restrict__ pk,
                         const uint4* __restrict__ feat,
                         const int* __restrict__ list, const int* __restrict__ nlist,
                         uint4* __restrict__ outf, int n) {
    int lane = threadIdx.x & 63;
    int g = lane >> 4;
    int r = lane & 15;
    int w = blockIdx.x * (blockDim.x >> 6) + (threadIdx.x >> 6);
    int limit = list ? *nlist : n;
    int idx = w * 4 + g;
    int node = (idx < limit) ? (list ? list[idx] : idx) : -1;
    int e = (node >= 0) ? head[node] : -1;
    int2 p = pk[e >= 0 ? e : 0];
    float a[8];
#pragma unroll
    for (int i = 0; i < 8; i++) a[i] = 0.f;
    int cnt = 0;

    while (__any(e >= 0)) {
        int srcn = (e >= 0) ? p.y : 0;
        uint4 u = feat[(size_t)srcn * 16 + r];       // 64 lanes -> 4 rows, 1 instr
        int en = (e >= 0 && p.x >= 0) ? p.x : 0;
        int2 pn = pk[en];
        bool act = e >= 0;
        float m = act ? 1.0f : 0.0f;
        a[0] += m * __uint_as_float(u.x << 16);
        a[1] += m * __uint_as_float(u.x & 0xffff0000u);
        a[2] += m * __uint_as_float(u.y << 16);
        a[3] += m * __uint_as_float(u.y & 0xffff0000u);
        a[4] += m * __uint_as_float(u.z << 16);
        a[5] += m * __uint_as_float(u.z & 0xffff0000u);
        a[6] += m * __uint_as_float(u.w << 16);
        a[7] += m * __uint_as_float(u.w & 0xffff0000u);
        cnt += act ? 1 : 0;
        e = act ? p.x : -1;
        p = pn;
    }
    if (node >= 0) {
        float ic = 1.0f / fmaxf((float)cnt, 1.0f);
        uint4 o;
        o.x = ((unsigned)f2b(a[1] * ic) << 16) | (unsigned)f2b(a[0] * ic);
        o.y = ((unsigned)f2b(a[3] * ic) << 16) | (unsigned)f2b(a[2] * ic);
        o.z = ((unsigned)f2b(a[5] * ic) << 16) | (unsigned)f2b(a[4] * ic);
        o.w = ((unsigned)f2b(a[7] * ic) << 16) | (unsigned)f2b(a[6] * ic);
        outf[(size_t)node * 16 + r] = o;
    }
}

// ---------------- MFMA dense: out = A@Wl.T (+ X@Wr.T) + b ----------------
template <int NCT, int TWO, int RELU, int OUTBF>
__global__ void k_mdense(const unsigned short* __restrict__ A,
                         const unsigned short* __restrict__ X,
                         const int* __restrict__ gidx,
                         const unsigned short* __restrict__ Wl,
                         const float* __restrict__ bl,
                         const unsigned short* __restrict__ Wr,
                         void* __restrict__ outp, int nrows) {
    const int OC = NCT * 16;
    int lane = threadIdx.x & 63;
    int wave = threadIdx.x >> 6;
    int rowBase = (blockIdx.x * 4 + wave) * 32;
    if (rowBase >= nrows) return;
    int rl = lane & 15;
    int ks = lane >> 4;
    int r0 = rowBase + rl, r1 = r0 + 16;
    int n0 = gidx ? gidx[r0] : r0;
    int n1 = gidx ? gidx[r1] : r1;
    f32x4 acc0[NCT], acc1[NCT];
#pragma unroll
    for (int ct = 0; ct < NCT; ct++) {
        acc0[ct] = (f32x4)0.f;
        acc1[ct] = (f32x4)0.f;
    }
#pragma unroll
    for (int pass = 0; pass < (TWO ? 2 : 1); pass++) {
        const unsigned short* Ain = pass ? X : A;
        const unsigned short* W = pass ? Wr : Wl;
        const s16x8* a0p = (const s16x8*)(Ain + (size_t)n0 * 128);
        const s16x8* a1p = (const s16x8*)(Ain + (size_t)n1 * 128);
#pragma unroll
        for (int kc = 0; kc < 4; kc++) {
            s16x8 af0 = a0p[kc * 4 + ks];
            s16x8 af1 = a1p[kc * 4 + ks];
#pragma unroll
            for (int ct = 0; ct < NCT; ct++) {
                const s16x8* bp = (const s16x8*)(W + (size_t)(ct * 16 + rl) * 128);
                s16x8 bf = bp[kc * 4 + ks];
                acc0[ct] = __builtin_amdgcn_mfma_f32_16x16x32_bf16(af0, bf, acc0[ct], 0, 0, 0);
                acc1[ct] = __builtin_amdgcn_mfma_f32_16x16x32_bf16(af1, bf, acc1[ct], 0, 0, 0);
            }
        }
    }
#pragma unroll
    for (int ct = 0; ct < NCT; ct++) {
        int col = ct * 16 + rl;
        float bj = bl[col];
#pragma unroll
        for (int j = 0; j < 4; j++) {
            int or0 = rowBase + ks * 4 + j;
            int or1 = or0 + 16;
            float v0 = acc0[ct][j] + bj;
            float v1 = acc1[ct][j] + bj;
            if (RELU) { v0 = fmaxf(v0, 0.f); v1 = fmaxf(v1, 0.f); }
            if (OUTBF) {
                ((unsigned short*)outp)[(size_t)or0 * OC + col] = f2b(v0);
                ((unsigned short*)outp)[(size_t)or1 * OC + col] = f2b(v1);
            } else {
                ((float*)outp)[(size_t)or0 * OC + col] = v0;
                ((float*)outp)[(size_t)or1 * OC + col] = v1;
            }
        }
    }
}

// ---------------- MFMA dense with fused BN+leaky on fp32 input (head FC2) ----------------
static __device__ __forceinline__ s16x8 bnpack(const float* __restrict__ p,
                                               const float* __restrict__ sc,
                                               const float* __restrict__ sh, float slope) {
    s16x8 r;
#pragma unroll
    for (int i = 0; i < 8; i++) {
        float y = p[i] * sc[i] + sh[i];
        y = (y >= 0.f) ? y : slope * y;
        r[i] = (short)f2b(y);
    }
    return r;
}

__global__ void k_mdense_bn(const float* __restrict__ Ain,  // nrows x 128 fp32
                            const float* __restrict__ scale, const float* __restrict__ shift,
                            const unsigned short* __restrict__ W,  // 64 x 128 bf16
                            const float* __restrict__ bl,
                            float* __restrict__ outp, int nrows, float slope) {
    const int NCT = 4, OC = 64;
    int lane = threadIdx.x & 63;
    int wave = threadIdx.x >> 6;
    int rowBase = (blockIdx.x * 4 + wave) * 32;
    if (rowBase >= nrows) return;
    int rl = lane & 15;
    int ks = lane >> 4;
    int r0 = rowBase + rl, r1 = r0 + 16;
    const float* a0p = Ain + (size_t)r0 * 128;
    const float* a1p = Ain + (size_t)r1 * 128;
    f32x4 acc0[NCT], acc1[NCT];
#pragma unroll
    for (int ct = 0; ct < NCT; ct++) {
        acc0[ct] = (f32x4)0.f;
        acc1[ct] = (f32x4)0.f;
    }
#pragma unroll
    for (int kc = 0; kc < 4; kc++) {
        int kb = kc * 32 + ks * 8;
        s16x8 af0 = bnpack(a0p + kb, scale + kb, shift + kb, slope);
        s16x8 af1 = bnpack(a1p + kb, scale + kb, shift + kb, slope);
#pragma unroll
        for (int ct = 0; ct < NCT; ct++) {
            const s16x8* bp = (const s16x8*)(W + (size_t)(ct * 16 + rl) * 128);
            s16x8 bf = bp[kc * 4 + ks];
            acc0[ct] = __builtin_amdgcn_mfma_f32_16x16x32_bf16(af0, bf, acc0[ct], 0, 0, 0);
            acc1[ct] = __builtin_amdgcn_mfma_f32_16x16x32_bf16(af1, bf, acc1[ct], 0, 0, 0);
        }
    }
#pragma unroll
    for (int ct = 0; ct < NCT; ct++) {
        int col = ct * 16 + rl;
        float bj = bl[col];
#pragma unroll
        for (int j = 0; j < 4; j++) {
            int or0 = rowBase + ks * 4 + j;
            int or1 = or0 + 16;
            outp[(size_t)or0 * OC + col] = acc0[ct][j] + bj;
            outp[(size_t)or1 * OC + col] = acc1[ct][j] + bj;
        }
    }
}

// ---------------- batchnorm ----------------
template <int C>
__global__ void k_bnstats(const float* __restrict__ z, float* __restrict__ gsum,
                          float* __restrict__ gsq, int nrows, int rowsPerBlock) {
    int t = threadIdx.x;
    int c = t % C;
    int g = t / C;
    const int G = 256 / C;
    int r0 = blockIdx.x * rowsPerBlock;
    int r1 = min(r0 + rowsPerBlock, nrows);
    float s = 0.f, q = 0.f;
    for (int r = r0 + g; r < r1; r += G) {
        float v = z[(size_t)r * C + c];
        s += v;
        q += v * v;
    }
    __shared__ float ls[256], lq[256];
    ls[t] = s;
    lq[t] = q;
    __syncthreads();
    if (t < C) {
        for (int g2 = 1; g2 < G; g2++) {
            s += ls[g2 * C + c];
            q += lq[g2 * C + c];
        }
        atomicAdd(&gsum[c], s);
        atomicAdd(&gsq[c], q);
    }
}

__global__ void k_bnprep(const float* __restrict__ gsum, const float* __restrict__ gsq,
                         const float* __restrict__ gamma, const float* __restrict__ beta,
                         float* __restrict__ scale, float* __restrict__ shift, int C, float invM) {
    int c = blockIdx.x * blockDim.x + threadIdx.x;
    if (c < C) {
        float mean = gsum[c] * invM;
        float var = gsq[c] * invM - mean * mean;
        float is = rsqrtf(var + EPSV);
        float sc = gamma[c] * is;
        scale[c] = sc;
        shift[c] = beta[c] - mean * sc;
    }
}

// ---------------- final fc3 with fused BN+leaky ----------------
__global__ void k_fc3_bn(const float* __restrict__ z2, const float* __restrict__ scale,
                         const float* __restrict__ shift, const float* __restrict__ w,
                         const float* __restrict__ b, float* __restrict__ out, int nrows) {
    int lane = threadIdx.x & 63;
    int m = blockIdx.x * (blockDim.x >> 6) + (threadIdx.x >> 6);
    if (m >= nrows) return;
    float y = z2[(size_t)m * 64 + lane] * scale[lane] + shift[lane];
    y = (y >= 0.f) ? y : 0.05f * y;
    float v = y * w[lane];
    for (int off = 32; off > 0; off >>= 1) v += __shfl_down(v, off);
    if (lane == 0) out[m] = v + b[0];
}

// ---------------- launch ----------------
extern "C" void kernel_launch(void* const* d_in, const int* in_sizes, int n_in,
                              void* d_out, int out_size, void* d_ws, size_t ws_size,
                              hipStream_t stream) {
    const float* x    = (const float*)d_in[0];
    const int*   ei   = (const int*)d_in[1];
    const int*   nidx = (const int*)d_in[2];
    const float* W1l  = (const float*)d_in[3];
    const float* b1   = (const float*)d_in[4];
    const float* W1r  = (const float*)d_in[5];
    const float* W2l  = (const float*)d_in[6];
    const float* b2   = (const float*)d_in[7];
    const float* W2r  = (const float*)d_in[8];
    const float* fcW1 = (const float*)d_in[9];
    const float* fcb1 = (const float*)d_in[10];
    const float* fcW2 = (const float*)d_in[11];
    const float* fcb2 = (const float*)d_in[12];
    const float* fcW3 = (const float*)d_in[13];
    const float* fcb3 = (const float*)d_in[14];
    const float* g1   = (const float*)d_in[15];
    const float* be1  = (const float*)d_in[16];
    const float* g2   = (const float*)d_in[17];
    const float* be2  = (const float*)d_in[18];

    const int N = in_sizes[0] / 128;
    const int E = in_sizes[1] / 2;
    const int M = in_sizes[2];
    const int* src = ei;
    const int* dst = ei + E;
    const int NBK = (N + 15) >> BSH;       // buckets (6250 for N=100k)
    const int NSLOT = NBK * SCAP;          // total slots (3.2M)

    char* ws = (char*)d_ws;
    size_t off = 0;
    unsigned short* xb  = (unsigned short*)(ws + off); off += (size_t)N * 128 * 2;
    unsigned short* sb  = (unsigned short*)(ws + off); off += (size_t)N * 128 * 2;
    unsigned short* h1b = (unsigned short*)(ws + off); off += (size_t)N * 128 * 2;
    unsigned short* z0b = (unsigned short*)(ws + off); off += (size_t)M * 128 * 2;
    float* z1           = (float*)(ws + off);          off += (size_t)M * 128 * 4;
    float* z2           = (float*)(ws + off);          off += (size_t)M * 64 * 4;
    unsigned short* Wb  = (unsigned short*)(ws + off); off += 90112 * 2;
    int2* pk       = (int2*)(ws + off);  off += (size_t)NSLOT * 8;
    int*  head     = (int*)(ws + off);   off += (size_t)N * 4;
    int*  bcur     = (int*)(ws + off);   off += (size_t)NBK * 4;
    int*  mark     = (int*)(ws + off);   off += (size_t)N * 4;
    int*  list     = (int*)(ws + off);   off += (size_t)M * 4;
    int*  nmarked  = (int*)(ws + off);   off += 64;
    float* gsum1   = (float*)(ws + off); off += 128 * 4;
    float* gsq1    = (float*)(ws + off); off += 128 * 4;
    float* scale1  = (float*)(ws + off); off += 128 * 4;
    float* shift1  = (float*)(ws + off); off += 128 * 4;
    float* gsum2   = (float*)(ws + off); off += 64 * 4;
    float* gsq2    = (float*)(ws + off); off += 64 * 4;
    float* scale2  = (float*)(ws + off); off += 64 * 4;
    float* shift2  = (float*)(ws + off); off += 64 * 4;
    float* out = (float*)d_out;

    hipMemsetAsync(head, 0xFF, (size_t)N * 4, stream);   // head = -1
    hipMemsetAsync(bcur, 0, (size_t)NBK * 4, stream);
    hipMemsetAsync(mark, 0, (size_t)N * 4, stream);
    hipMemsetAsync(nmarked, 0, 4, stream);
    hipMemsetAsync(gsum1, 0, (128 + 128 + 128 + 128 + 64 + 64 + 64 + 64) * 4, stream);

    // conversions (independent of graph build)
    k_wconv<<<(90112 + 255) / 256, 256, 0, stream>>>(W1l, W1r, W2l, W2r, fcW1, fcW2, Wb);
    k_tobf16<<<2048, 256, 0, stream>>>(x, xb, N * 128 / 4);

    // graph build: bucket-clustered per-node linked lists
    k_link2<<<(E + 255) / 256, 256, 0, stream>>>(src, dst, head, bcur, pk, E);
    k_mark<<<(M + 255) / 256, 256, 0, stream>>>(nidx, mark, list, nmarked, M);

    // layer 1: aggregate all nodes
    {
        int waves = (N + 3) / 4;
        k_aggr_g<<<(waves + 3) / 4, 256, 0, stream>>>(
            head, pk, (const uint4*)xb, nullptr, nullptr, (uint4*)sb, N);
    }
    k_mdense<8, 1, 1, 1><<<(N / 32 + 3) / 4, 256, 0, stream>>>(
        sb, xb, nullptr, Wb + 0, b1, Wb + 16384, h1b, N);

    // layer 2: aggregate only marked dst nodes
    {
        int waves = (M + 3) / 4;
        k_aggr_g<<<(waves + 3) / 4, 256, 0, stream>>>(
            head, pk, (const uint4*)h1b, list, nmarked, (uint4*)sb, N);
    }
    k_mdense<8, 1, 0, 1><<<(M / 32 + 3) / 4, 256, 0, stream>>>(
        sb, h1b, nidx, Wb + 32768, b2, Wb + 49152, z0b, M);

    // MLP head: fc1 -> bn-stats -> prep -> [bn+fc2 fused] -> bn-stats -> prep -> [bn+fc3 fused]
    k_mdense<8, 0, 0, 0><<<(M / 32 + 3) / 4, 256, 0, stream>>>(
        z0b, nullptr, nullptr, Wb + 65536, fcb1, nullptr, z1, M);
    k_bnstats<128><<<(M + 399) / 400, 256, 0, stream>>>(z1, gsum1, gsq1, M, 400);
    k_bnprep<<<1, 128, 0, stream>>>(gsum1, gsq1, g1, be1, scale1, shift1, 128, 1.0f / M);

    k_mdense_bn<<<(M / 32 + 3) / 4, 256, 0, stream>>>(
        z1, scale1, shift1, Wb + 81920, fcb2, z2, M, 0.1f);
    k_bnstats<64><<<(M + 399) / 400, 256, 0, stream>>>(z2, gsum2, gsq2, M, 400);
    k_bnprep<<<1, 64, 0, stream>>>(gsum2, gsq2, g2, be2, scale2, shift2, 64, 1.0f / M);

    k_fc3_bn<<<(M + 3) / 4, 256, 0, stream>>>(z2, scale2, shift2, fcW3, fcb3, out, M);
}

// Round 12
// 485.514 us; speedup vs baseline: 1.1734x; 1.1734x over previous
//
#include <hip/hip_runtime.h>
#include <hip/hip_bf16.h>

#define EPSV 1e-5f

typedef __attribute__((ext_vector_type(8))) short s16x8;
typedef __attribute__((ext_vector_type(4))) float f32x4;

static __device__ __forceinline__ unsigned short f2b(float f) {
    __hip_bfloat16 h = __float2bfloat16(f);
    return *reinterpret_cast<unsigned short*>(&h);
}

// ---------------- linked-list graph build (coalesced pk writes) ----------------
// head[node] -> most recent edge id; pk[e] = {next_edge, src_node}

__global__ void k_link(const int* __restrict__ src, const int* __restrict__ dst,
                       int* __restrict__ head, int2* __restrict__ pk, int E) {
    int e = blockIdx.x * blockDim.x + threadIdx.x;
    if (e < E) {
        int h = atomicExch(&head[dst[e]], e);
        pk[e] = make_int2(h, src[e]);
    }
}

__global__ void k_mark(const int* __restrict__ nidx, int* __restrict__ mark,
                       int* __restrict__ list, int* __restrict__ nmarked, int M) {
    int m = blockIdx.x * blockDim.x + threadIdx.x;
    if (m < M) {
        int n = nidx[m];
        if (atomicExch(&mark[n], 1) == 0) list[atomicAdd(nmarked, 1)] = n;
    }
}

// ---------------- conversions ----------------

__global__ void k_tobf16(const float* __restrict__ in, unsigned short* __restrict__ out, int n4) {
    int i = blockIdx.x * blockDim.x + threadIdx.x;
    int stride = gridDim.x * blockDim.x;
    for (; i < n4; i += stride) {
        float4 v = ((const float4*)in)[i];
        ushort4 u;
        u.x = f2b(v.x); u.y = f2b(v.y); u.z = f2b(v.z); u.w = f2b(v.w);
        ((ushort4*)out)[i] = u;
    }
}

// offsets: W1l 0, W1r 16384, W2l 32768, W2r 49152, fcW1 65536, fcW2 81920 (total 90112)
__global__ void k_wconv(const float* __restrict__ W1l, const float* __restrict__ W1r,
                        const float* __restrict__ W2l, const float* __restrict__ W2r,
                        const float* __restrict__ fcW1, const float* __restrict__ fcW2,
                        unsigned short* __restrict__ Wb) {
    int i = blockIdx.x * blockDim.x + threadIdx.x;
    if (i >= 90112) return;
    float v;
    if (i < 16384) v = W1l[i];
    else if (i < 32768) v = W1r[i - 16384];
    else if (i < 49152) v = W2l[i - 32768];
    else if (i < 65536) v = W2r[i - 49152];
    else if (i < 81920) v = fcW1[i - 65536];
    else v = fcW2[i - 81920];
    Wb[i] = f2b(v);
}

// ---------------- aggregation: 16-lane-group dwordx4 chain walk ----------------
__global__ void k_aggr_g(const int* __restrict__ head, const int2* __restrict__ pk,
                         const uint4* __restrict__ feat,
                         const int* __restrict__ list, const int* __restrict__ nlist,
                         uint4* __restrict__ outf, int n) {
    int lane = threadIdx.x & 63;
    int g = lane >> 4;
    int r = lane & 15;
    int w = blockIdx.x * (blockDim.x >> 6) + (threadIdx.x >> 6);
    int limit = list ? *nlist : n;
    int idx = w * 4 + g;
    int node = (idx < limit) ? (list ? list[idx] : idx) : -1;
    int e = (node >= 0) ? head[node] : -1;
    int2 p = pk[e >= 0 ? e : 0];
    float a[8];
#pragma unroll
    for (int i = 0; i < 8; i++) a[i] = 0.f;
    int cnt = 0;

    while (__any(e >= 0)) {
        int srcn = (e >= 0) ? p.y : 0;
        uint4 u = feat[(size_t)srcn * 16 + r];       // 64 lanes -> 4 rows, 1 instr
        int en = (e >= 0 && p.x >= 0) ? p.x : 0;
        int2 pn = pk[en];
        bool act = e >= 0;
        float m = act ? 1.0f : 0.0f;
        a[0] += m * __uint_as_float(u.x << 16);
        a[1] += m * __uint_as_float(u.x & 0xffff0000u);
        a[2] += m * __uint_as_float(u.y << 16);
        a[3] += m * __uint_as_float(u.y & 0xffff0000u);
        a[4] += m * __uint_as_float(u.z << 16);
        a[5] += m * __uint_as_float(u.z & 0xffff0000u);
        a[6] += m * __uint_as_float(u.w << 16);
        a[7] += m * __uint_as_float(u.w & 0xffff0000u);
        cnt += act ? 1 : 0;
        e = act ? p.x : -1;
        p = pn;
    }
    if (node >= 0) {
        float ic = 1.0f / fmaxf((float)cnt, 1.0f);
        uint4 o;
        o.x = ((unsigned)f2b(a[1] * ic) << 16) | (unsigned)f2b(a[0] * ic);
        o.y = ((unsigned)f2b(a[3] * ic) << 16) | (unsigned)f2b(a[2] * ic);
        o.z = ((unsigned)f2b(a[5] * ic) << 16) | (unsigned)f2b(a[4] * ic);
        o.w = ((unsigned)f2b(a[7] * ic) << 16) | (unsigned)f2b(a[6] * ic);
        outf[(size_t)node * 16 + r] = o;
    }
}

// ---------------- MFMA dense: out = A@Wl.T (+ X@Wr.T) + b ----------------
template <int NCT, int TWO, int RELU, int OUTBF>
__global__ void k_mdense(const unsigned short* __restrict__ A,
                         const unsigned short* __restrict__ X,
                         const int* __restrict__ gidx,
                         const unsigned short* __restrict__ Wl,
                         const float* __restrict__ bl,
                         const unsigned short* __restrict__ Wr,
                         void* __restrict__ outp, int nrows) {
    const int OC = NCT * 16;
    int lane = threadIdx.x & 63;
    int wave = threadIdx.x >> 6;
    int rowBase = (blockIdx.x * 4 + wave) * 32;
    if (rowBase >= nrows) return;
    int rl = lane & 15;
    int ks = lane >> 4;
    int r0 = rowBase + rl, r1 = r0 + 16;
    int n0 = gidx ? gidx[r0] : r0;
    int n1 = gidx ? gidx[r1] : r1;
    f32x4 acc0[NCT], acc1[NCT];
#pragma unroll
    for (int ct = 0; ct < NCT; ct++) {
        acc0[ct] = (f32x4)0.f;
        acc1[ct] = (f32x4)0.f;
    }
#pragma unroll
    for (int pass = 0; pass < (TWO ? 2 : 1); pass++) {
        const unsigned short* Ain = pass ? X : A;
        const unsigned short* W = pass ? Wr : Wl;
        const s16x8* a0p = (const s16x8*)(Ain + (size_t)n0 * 128);
        const s16x8* a1p = (const s16x8*)(Ain + (size_t)n1 * 128);
#pragma unroll
        for (int kc = 0; kc < 4; kc++) {
            s16x8 af0 = a0p[kc * 4 + ks];
            s16x8 af1 = a1p[kc * 4 + ks];
#pragma unroll
            for (int ct = 0; ct < NCT; ct++) {
                const s16x8* bp = (const s16x8*)(W + (size_t)(ct * 16 + rl) * 128);
                s16x8 bf = bp[kc * 4 + ks];
                acc0[ct] = __builtin_amdgcn_mfma_f32_16x16x32_bf16(af0, bf, acc0[ct], 0, 0, 0);
                acc1[ct] = __builtin_amdgcn_mfma_f32_16x16x32_bf16(af1, bf, acc1[ct], 0, 0, 0);
            }
        }
    }
#pragma unroll
    for (int ct = 0; ct < NCT; ct++) {
        int col = ct * 16 + rl;
        float bj = bl[col];
#pragma unroll
        for (int j = 0; j < 4; j++) {
            int or0 = rowBase + ks * 4 + j;
            int or1 = or0 + 16;
            float v0 = acc0[ct][j] + bj;
            float v1 = acc1[ct][j] + bj;
            if (RELU) { v0 = fmaxf(v0, 0.f); v1 = fmaxf(v1, 0.f); }
            if (OUTBF) {
                ((unsigned short*)outp)[(size_t)or0 * OC + col] = f2b(v0);
                ((unsigned short*)outp)[(size_t)or1 * OC + col] = f2b(v1);
            } else {
                ((float*)outp)[(size_t)or0 * OC + col] = v0;
                ((float*)outp)[(size_t)or1 * OC + col] = v1;
            }
        }
    }
}

// ---------------- MFMA dense with fused BN+leaky on fp32 input (head FC2) ----------------
static __device__ __forceinline__ s16x8 bnpack(const float* __restrict__ p,
                                               const float* __restrict__ sc,
                                               const float* __restrict__ sh, float slope) {
    s16x8 r;
#pragma unroll
    for (int i = 0; i < 8; i++) {
        float y = p[i] * sc[i] + sh[i];
        y = (y >= 0.f) ? y : slope * y;
        r[i] = (short)f2b(y);
    }
    return r;
}

__global__ void k_mdense_bn(const float* __restrict__ Ain,  // nrows x 128 fp32
                            const float* __restrict__ scale, const float* __restrict__ shift,
                            const unsigned short* __restrict__ W,  // 64 x 128 bf16
                            const float* __restrict__ bl,
                            float* __restrict__ outp, int nrows, float slope) {
    const int NCT = 4, OC = 64;
    int lane = threadIdx.x & 63;
    int wave = threadIdx.x >> 6;
    int rowBase = (blockIdx.x * 4 + wave) * 32;
    if (rowBase >= nrows) return;
    int rl = lane & 15;
    int ks = lane >> 4;
    int r0 = rowBase + rl, r1 = r0 + 16;
    const float* a0p = Ain + (size_t)r0 * 128;
    const float* a1p = Ain + (size_t)r1 * 128;
    f32x4 acc0[NCT], acc1[NCT];
#pragma unroll
    for (int ct = 0; ct < NCT; ct++) {
        acc0[ct] = (f32x4)0.f;
        acc1[ct] = (f32x4)0.f;
    }
#pragma unroll
    for (int kc = 0; kc < 4; kc++) {
        int kb = kc * 32 + ks * 8;
        s16x8 af0 = bnpack(a0p + kb, scale + kb, shift + kb, slope);
        s16x8 af1 = bnpack(a1p + kb, scale + kb, shift + kb, slope);
#pragma unroll
        for (int ct = 0; ct < NCT; ct++) {
            const s16x8* bp = (const s16x8*)(W + (size_t)(ct * 16 + rl) * 128);
            s16x8 bf = bp[kc * 4 + ks];
            acc0[ct] = __builtin_amdgcn_mfma_f32_16x16x32_bf16(af0, bf, acc0[ct], 0, 0, 0);
            acc1[ct] = __builtin_amdgcn_mfma_f32_16x16x32_bf16(af1, bf, acc1[ct], 0, 0, 0);
        }
    }
#pragma unroll
    for (int ct = 0; ct < NCT; ct++) {
        int col = ct * 16 + rl;
        float bj = bl[col];
#pragma unroll
        for (int j = 0; j < 4; j++) {
            int or0 = rowBase + ks * 4 + j;
            int or1 = or0 + 16;
            outp[(size_t)or0 * OC + col] = acc0[ct][j] + bj;
            outp[(size_t)or1 * OC + col] = acc1[ct][j] + bj;
        }
    }
}

// ---------------- batchnorm ----------------
template <int C>
__global__ void k_bnstats(const float* __restrict__ z, float* __restrict__ gsum,
                          float* __restrict__ gsq, int nrows, int rowsPerBlock) {
    int t = threadIdx.x;
    int c = t % C;
    int g = t / C;
    const int G = 256 / C;
    int r0 = blockIdx.x * rowsPerBlock;
    int r1 = min(r0 + rowsPerBlock, nrows);
    float s = 0.f, q = 0.f;
    for (int r = r0 + g; r < r1; r += G) {
        float v = z[(size_t)r * C + c];
        s += v;
        q += v * v;
    }
    __shared__ float ls[256], lq[256];
    ls[t] = s;
    lq[t] = q;
    __syncthreads();
    if (t < C) {
        for (int g2 = 1; g2 < G; g2++) {
            s += ls[g2 * C + c];
            q += lq[g2 * C + c];
        }
        atomicAdd(&gsum[c], s);
        atomicAdd(&gsq[c], q);
    }
}

__global__ void k_bnprep(const float* __restrict__ gsum, const float* __restrict__ gsq,
                         const float* __restrict__ gamma, const float* __restrict__ beta,
                         float* __restrict__ scale, float* __restrict__ shift, int C, float invM) {
    int c = blockIdx.x * blockDim.x + threadIdx.x;
    if (c < C) {
        float mean = gsum[c] * invM;
        float var = gsq[c] * invM - mean * mean;
        float is = rsqrtf(var + EPSV);
        float sc = gamma[c] * is;
        scale[c] = sc;
        shift[c] = beta[c] - mean * sc;
    }
}

// ---------------- final fc3 with fused BN+leaky ----------------
__global__ void k_fc3_bn(const float* __restrict__ z2, const float* __restrict__ scale,
                         const float* __restrict__ shift, const float* __restrict__ w,
                         const float* __restrict__ b, float* __restrict__ out, int nrows) {
    int lane = threadIdx.x & 63;
    int m = blockIdx.x * (blockDim.x >> 6) + (threadIdx.x >> 6);
    if (m >= nrows) return;
    float y = z2[(size_t)m * 64 + lane] * scale[lane] + shift[lane];
    y = (y >= 0.f) ? y : 0.05f * y;
    float v = y * w[lane];
    for (int off = 32; off > 0; off >>= 1) v += __shfl_down(v, off);
    if (lane == 0) out[m] = v + b[0];
}

// ---------------- launch ----------------
extern "C" void kernel_launch(void* const* d_in, const int* in_sizes, int n_in,
                              void* d_out, int out_size, void* d_ws, size_t ws_size,
                              hipStream_t stream) {
    const float* x    = (const float*)d_in[0];
    const int*   ei   = (const int*)d_in[1];
    const int*   nidx = (const int*)d_in[2];
    const float* W1l  = (const float*)d_in[3];
    const float* b1   = (const float*)d_in[4];
    const float* W1r  = (const float*)d_in[5];
    const float* W2l  = (const float*)d_in[6];
    const float* b2   = (const float*)d_in[7];
    const float* W2r  = (const float*)d_in[8];
    const float* fcW1 = (const float*)d_in[9];
    const float* fcb1 = (const float*)d_in[10];
    const float* fcW2 = (const float*)d_in[11];
    const float* fcb2 = (const float*)d_in[12];
    const float* fcW3 = (const float*)d_in[13];
    const float* fcb3 = (const float*)d_in[14];
    const float* g1   = (const float*)d_in[15];
    const float* be1  = (const float*)d_in[16];
    const float* g2   = (const float*)d_in[17];
    const float* be2  = (const float*)d_in[18];

    const int N = in_sizes[0] / 128;
    const int E = in_sizes[1] / 2;
    const int M = in_sizes[2];
    const int* src = ei;
    const int* dst = ei + E;

    char* ws = (char*)d_ws;
    size_t off = 0;
    unsigned short* xb  = (unsigned short*)(ws + off); off += (size_t)N * 128 * 2;
    unsigned short* sb  = (unsigned short*)(ws + off); off += (size_t)N * 128 * 2;
    unsigned short* h1b = (unsigned short*)(ws + off); off += (size_t)N * 128 * 2;
    unsigned short* z0b = (unsigned short*)(ws + off); off += (size_t)M * 128 * 2;
    float* z1           = (float*)(ws + off);          off += (size_t)M * 128 * 4;
    float* z2           = (float*)(ws + off);          off += (size_t)M * 64 * 4;
    unsigned short* Wb  = (unsigned short*)(ws + off); off += 90112 * 2;
    int2* pk       = (int2*)(ws + off);  off += (size_t)E * 8;
    int*  head     = (int*)(ws + off);   off += (size_t)N * 4;
    int*  mark     = (int*)(ws + off);   off += (size_t)N * 4;
    int*  list     = (int*)(ws + off);   off += (size_t)M * 4;
    int*  nmarked  = (int*)(ws + off);   off += 64;
    float* gsum1   = (float*)(ws + off); off += 128 * 4;
    float* gsq1    = (float*)(ws + off); off += 128 * 4;
    float* scale1  = (float*)(ws + off); off += 128 * 4;
    float* shift1  = (float*)(ws + off); off += 128 * 4;
    float* gsum2   = (float*)(ws + off); off += 64 * 4;
    float* gsq2    = (float*)(ws + off); off += 64 * 4;
    float* scale2  = (float*)(ws + off); off += 64 * 4;
    float* shift2  = (float*)(ws + off); off += 64 * 4;
    float* out = (float*)d_out;

    hipMemsetAsync(head, 0xFF, (size_t)N * 4, stream);   // head = -1
    hipMemsetAsync(mark, 0, (size_t)N * 4, stream);
    hipMemsetAsync(nmarked, 0, 4, stream);
    hipMemsetAsync(gsum1, 0, (128 + 128 + 128 + 128 + 64 + 64 + 64 + 64) * 4, stream);

    // conversions (independent of graph build)
    k_wconv<<<(90112 + 255) / 256, 256, 0, stream>>>(W1l, W1r, W2l, W2r, fcW1, fcW2, Wb);
    k_tobf16<<<2048, 256, 0, stream>>>(x, xb, N * 128 / 4);

    // graph build: per-node linked lists (coalesced pk writes)
    k_link<<<(E + 255) / 256, 256, 0, stream>>>(src, dst, head, pk, E);
    k_mark<<<(M + 255) / 256, 256, 0, stream>>>(nidx, mark, list, nmarked, M);

    // layer 1: aggregate all nodes
    {
        int waves = (N + 3) / 4;
        k_aggr_g<<<(waves + 3) / 4, 256, 0, stream>>>(
            head, pk, (const uint4*)xb, nullptr, nullptr, (uint4*)sb, N);
    }
    k_mdense<8, 1, 1, 1><<<(N / 32 + 3) / 4, 256, 0, stream>>>(
        sb, xb, nullptr, Wb + 0, b1, Wb + 16384, h1b, N);

    // layer 2: aggregate only marked dst nodes
    {
        int waves = (M + 3) / 4;
        k_aggr_g<<<(waves + 3) / 4, 256, 0, stream>>>(
            head, pk, (const uint4*)h1b, list, nmarked, (uint4*)sb, N);
    }
    k_mdense<8, 1, 0, 1><<<(M / 32 + 3) / 4, 256, 0, stream>>>(
        sb, h1b, nidx, Wb + 32768, b2, Wb + 49152, z0b, M);

    // MLP head: fc1 -> bn-stats -> prep -> [bn+fc2 fused] -> bn-stats -> prep -> [bn+fc3 fused]
    k_mdense<8, 0, 0, 0><<<(M / 32 + 3) / 4, 256, 0, stream>>>(
        z0b, nullptr, nullptr, Wb + 65536, fcb1, nullptr, z1, M);
    k_bnstats<128><<<(M + 399) / 400, 256, 0, stream>>>(z1, gsum1, gsq1, M, 400);
    k_bnprep<<<1, 128, 0, stream>>>(gsum1, gsq1, g1, be1, scale1, shift1, 128, 1.0f / M);

    k_mdense_bn<<<(M / 32 + 3) / 4, 256, 0, stream>>>(
        z1, scale1, shift1, Wb + 81920, fcb2, z2, M, 0.1f);
    k_bnstats<64><<<(M + 399) / 400, 256, 0, stream>>>(z2, gsum2, gsq2, M, 400);
    k_bnprep<<<1, 64, 0, stream>>>(gsum2, gsq2, g2, be2, scale2, shift2, 64, 1.0f / M);

    k_fc3_bn<<<(M + 3) / 4, 256, 0, stream>>>(z2, scale2, shift2, fcW3, fcb3, out, M);
}